// Round 9
// baseline (2294.503 us; speedup 1.0000x reference)
//
#include <hip/hip_runtime.h>

#define BB 256
#define TT 2048
#define SS 32
#define NN 19
#define NCLASS 10
#define NUNFOLD 6
#define EPSV 1e-8f
#define LOG2E 1.4426950408889634f

// ---------------------------------------------------------------------------
// Phase 0: fold sensory params once -> pqws[j][s] = {P, Qn, W, A}
// exponent = P + Qn*x  (== LOG2E*sigma*(mu - (iw*x+ib)))
// ---------------------------------------------------------------------------
__global__ void ltc_fold_kernel(const float* __restrict__ iw,
                                const float* __restrict__ ib,
                                const float* __restrict__ smu,
                                const float* __restrict__ ssig,
                                const float* __restrict__ sw,
                                const float* __restrict__ serev,
                                const int* __restrict__ smask,
                                float4* __restrict__ pqws)
{
    int idx = blockIdx.x * 256 + threadIdx.x;
    if (idx >= SS * NN) return;
    int j = idx / SS;
    int s = idx % SS;
    int src = s * NN + j;
    float sg = ssig[src] * LOG2E;
    float P  = sg * smu[src] - sg * ib[s];
    float Qn = -sg * iw[s];
    float wm = sw[src] * (float)smask[src];
    pqws[idx] = make_float4(P, Qn, wm, wm * serev[src]);
}

// ---------------------------------------------------------------------------
// Phase 1: sensory precompute v3.  Thread = one (t,b,j) output.
// Params: 32 wave-uniform float4 broadcast loads from pqws (L1 fast path,
// replaces R6's 608 LDS reads/thread).  Grid is j-fast so the 19x re-reads
// of each x row stay L2-resident.
// ---------------------------------------------------------------------------
__global__ void __launch_bounds__(256)
ltc_sens_kernel(const float* __restrict__ x,
                const float4* __restrict__ pqws,
                float* __restrict__ sens,
                int t0, int tc)
{
    int j   = blockIdx.x % NN;
    int ctb = blockIdx.x / NN;
    long gtb = (long)ctb * 256 + threadIdx.x;
    if (gtb >= (long)tc * BB) return;
    int trel = (int)(gtb % tc);          // t fast within wave -> x rows adjacent
    int b    = (int)(gtb / tc);
    int t    = t0 + trel;

    const float4* pp  = pqws + j * SS;
    const float4* xr4 = (const float4*)(x + ((long)b * TT + t) * SS);

    float num = 0.f, den = 0.f;
#pragma unroll
    for (int q4 = 0; q4 < SS / 4; q4++) {
        float4 xv = xr4[q4];
        float4 c0 = pp[4 * q4 + 0];
        float4 c1 = pp[4 * q4 + 1];
        float4 c2 = pp[4 * q4 + 2];
        float4 c3 = pp[4 * q4 + 3];
        {
            float e0 = __builtin_amdgcn_exp2f(fmaf(c0.y, xv.x, c0.x));
            float e1 = __builtin_amdgcn_exp2f(fmaf(c1.y, xv.y, c1.x));
            float t0v = 1.0f + e0, t1v = 1.0f + e1;
            float rD = __builtin_amdgcn_rcpf(t0v * t1v);
            num = fmaf(fmaf(c0.w, t1v, c1.w * t0v), rD, num);
            den = fmaf(fmaf(c0.z, t1v, c1.z * t0v), rD, den);
        }
        {
            float e0 = __builtin_amdgcn_exp2f(fmaf(c2.y, xv.z, c2.x));
            float e1 = __builtin_amdgcn_exp2f(fmaf(c3.y, xv.w, c3.x));
            float t0v = 1.0f + e0, t1v = 1.0f + e1;
            float rD = __builtin_amdgcn_rcpf(t0v * t1v);
            num = fmaf(fmaf(c2.w, t1v, c3.w * t0v), rD, num);
            den = fmaf(fmaf(c2.z, t1v, c3.z * t0v), rD, den);
        }
    }
    float* o = sens + ((long)trel * BB + b) * (2 * NN);
    o[j]      = num;
    o[NN + j] = den;
}

// ---------------------------------------------------------------------------
template <int CTRL>
__device__ __forceinline__ float dpp_shl(float x)
{
    return __int_as_float(__builtin_amdgcn_update_dpp(
        0, __float_as_int(x), CTRL, 0xf, 0xf, true));
}

__device__ __forceinline__ float bperm(int addr4, float v)
{
    return __int_as_float(__builtin_amdgcn_ds_bpermute(addr4, __float_as_int(v)));
}

// leader lane of pre-neuron i (rows 2,3 offset +1 => all 19 leaders in
// distinct LDS banks -> conflict-free bpermute broadcast)
__device__ __forceinline__ int lead_lane(int i)
{
    int rw = i / 5;
    return 16 * rw + 3 * (i % 5) + (rw >= 2 ? 1 : 0);
}

// ---------------------------------------------------------------------------
// Templated scan main loop — exact R8 structure (measured 1886us,
// ~368 cy/unfold).  One batch per wave, scalar math, sparse slots.
// ---------------------------------------------------------------------------
template <int KU>
__device__ __forceinline__ void run_scan(
    int lane, int jc, bool pad, int r,
    const float (&sg2)[8], const float (&sb2)[8],
    const float (&Aa)[8], const float (&Wm)[8], const int (&src4)[8],
    float cmt, float glvl, float cgl, float ow0, float ob0,
    const float* __restrict__ sens, float* __restrict__ outbuf,
    float* __restrict__ vstate, int b, int t0, int tc, int initv)
{
    float v = initv ? 0.f : vstate[b * NN + jc];
    const float* sp0 = sens + (long)b * (2 * NN);
    float sn = sp0[jc], sd = sp0[NN + jc];

    for (int t = 0; t < tc; t++) {
        float sn_nx = sn, sd_nx = sd;
        if (t + 1 < tc) {
            const float* spn = sens + ((long)(t + 1) * BB + b) * (2 * NN);
            sn_nx = spn[jc]; sd_nx = spn[NN + jc];
        }
        float nbase = glvl + sn, dbase = cgl + sd;

#pragma unroll
        for (int u = 0; u < NUNFOLD; u++) {
            float vi[KU];
#pragma unroll
            for (int k = 0; k < KU; k++) vi[k] = bperm(src4[k], v);

            float n = fmaf(cmt, v, nbase);

            float ev[KU];
#pragma unroll
            for (int k = 0; k < KU; k++)
                ev[k] = __builtin_amdgcn_exp2f(fmaf(sg2[k], vi[k], sb2[k]));

            float pn = 0.f, pd = 0.f;
            constexpr int NP = KU / 2;
#pragma unroll
            for (int p = 0; p < NP; p++) {
                float t0v = 1.0f + ev[2 * p];
                float t1v = 1.0f + ev[2 * p + 1];
                float rD  = __builtin_amdgcn_rcpf(t0v * t1v);
                pn = fmaf(fmaf(Aa[2 * p], t1v, Aa[2 * p + 1] * t0v), rD, pn);
                pd = fmaf(fmaf(Wm[2 * p], t1v, Wm[2 * p + 1] * t0v), rD, pd);
            }
            if (KU & 1) {
                float s1 = __builtin_amdgcn_rcpf(1.0f + ev[KU - 1]);
                pn = fmaf(Aa[KU - 1], s1, pn);
                pd = fmaf(Wm[KU - 1], s1, pd);
            }

            // 3-lane DPP reduce: triple base lane gets the full sum
            pn = pn + dpp_shl<0x101>(pn) + dpp_shl<0x102>(pn);
            pd = pd + dpp_shl<0x101>(pd) + dpp_shl<0x102>(pd);

            // all lanes update; only leader lanes are ever read (bperm/store)
            v = (n + pn) * __builtin_amdgcn_rcpf(dbase + pd);
        }
        if (lane == 0) outbuf[(long)b * TT + (t0 + t)] = fmaf(v, ow0, ob0);
        sn = sn_nx; sd = sd_nx;
    }
    if (!pad && r == 0) vstate[b * NN + jc] = v;
}

// ---------------------------------------------------------------------------
// Phase 2 kernel: balanced sparse slot lists (mask ~50% zero), wave-uniform
// KU dispatch, ONE batch per wave.
// ---------------------------------------------------------------------------
__global__ void __launch_bounds__(64, 1)
ltc_scan_kernel(const float* __restrict__ mu,  const float* __restrict__ sigma,
                const float* __restrict__ w,   const float* __restrict__ erev,
                const int* __restrict__ mask,
                const float* __restrict__ gleak, const float* __restrict__ vleak,
                const float* __restrict__ cm,
                const float* __restrict__ ow,  const float* __restrict__ ob,
                const float* __restrict__ sens, float* __restrict__ outbuf,
                float* __restrict__ vstate, int t0, int tc, int initv)
{
    int b    = blockIdx.x;
    int lane = threadIdx.x;
    int row  = lane >> 4;
    int pos  = lane & 15;
    int off  = (row >= 2) ? 1 : 0;
    int posr = pos - off;                       // row>=2: pos 0 is pad
    int jq   = (posr < 0) ? 5 : posr / 3;       // 5 => pad
    int rr   = (posr < 0) ? 0 : posr - 3 * jq;
    int j    = row * 5 + jq;
    bool pad = (jq >= 5) || (j >= NN);
    int jc   = pad ? 0 : j;
    int r    = pad ? 0 : rr;

    // balanced sparse slot lists: the a-th active pre-neuron of column j goes
    // to lane r = a%3, slot a/3.  Dummy slots: weights 0 (exact).
    float sg2[8], sb2[8], Aa[8], Wm[8];
    int src4[8];
    int used = 0;
#pragma unroll
    for (int s = 0; s < 8; s++) {
        int target = 3 * s + r;
        int ii = -1, a = 0;
        for (int i = 0; i < NN; i++) {
            if (mask[i * NN + jc] != 0) {
                if (a == target) ii = i;
                a++;
            }
        }
        bool ok = (ii >= 0) && !pad;
        int iu  = ok ? ii : 0;
        int idx = iu * NN + jc;
        float sgv = sigma[idx];
        float wmm = ok ? w[idx] : 0.f;          // mask[idx]==1 when ok
        sg2[s] = ok ? (-LOG2E * sgv) : 0.f;
        sb2[s] = ok ? (LOG2E * sgv * mu[idx]) : 0.f;
        Aa[s]  = wmm * erev[idx];
        Wm[s]  = wmm;
        src4[s] = lead_lane(iu) << 2;
        if (ok) used = s + 1;
    }

    // wave-max of used slots (prologue-only shuffles)
    int km = used;
#pragma unroll
    for (int o = 1; o < 64; o <<= 1) {
        int other = __shfl_xor(km, o, 64);
        km = km > other ? km : other;
    }

    float cmt   = cm[jc] * (float)NUNFOLD;
    float gl    = gleak[jc];
    float glvl  = gl * vleak[jc];
    float cgl   = cmt + gl + EPSV;
    float ow0 = ow[0], ob0 = ob[0];

    if (km <= 3)
        run_scan<3>(lane, jc, pad, r, sg2, sb2, Aa, Wm, src4, cmt, glvl, cgl,
                    ow0, ob0, sens, outbuf, vstate, b, t0, tc, initv);
    else if (km == 4)
        run_scan<4>(lane, jc, pad, r, sg2, sb2, Aa, Wm, src4, cmt, glvl, cgl,
                    ow0, ob0, sens, outbuf, vstate, b, t0, tc, initv);
    else if (km == 5)
        run_scan<5>(lane, jc, pad, r, sg2, sb2, Aa, Wm, src4, cmt, glvl, cgl,
                    ow0, ob0, sens, outbuf, vstate, b, t0, tc, initv);
    else if (km == 6)
        run_scan<6>(lane, jc, pad, r, sg2, sb2, Aa, Wm, src4, cmt, glvl, cgl,
                    ow0, ob0, sens, outbuf, vstate, b, t0, tc, initv);
    else
        run_scan<7>(lane, jc, pad, r, sg2, sb2, Aa, Wm, src4, cmt, glvl, cgl,
                    ow0, ob0, sens, outbuf, vstate, b, t0, tc, initv);
}

// ---------------------------------------------------------------------------
// Phase 3: FC head.  One wave per (b, c).
// ---------------------------------------------------------------------------
__global__ void ltc_fc_kernel(const float* __restrict__ outbuf,
                              const float* __restrict__ fcw,
                              const float* __restrict__ fcb,
                              float* __restrict__ out)
{
    int bc = blockIdx.x;
    int b = bc / NCLASS;
    int c = bc % NCLASS;
    const float* xr = outbuf + (long)b * TT;
    const float* wr = fcw + (long)c * TT;
    float acc = 0.f;
    for (int t = threadIdx.x; t < TT; t += 64)
        acc = fmaf(xr[t], wr[t], acc);
#pragma unroll
    for (int off = 32; off > 0; off >>= 1)
        acc += __shfl_down(acc, off, 64);
    if (threadIdx.x == 0) out[bc] = acc + fcb[c];
}

// ---------------------------------------------------------------------------
extern "C" void kernel_launch(void* const* d_in, const int* in_sizes, int n_in,
                              void* d_out, int out_size, void* d_ws, size_t ws_size,
                              hipStream_t stream)
{
    const float* x     = (const float*)d_in[0];
    const float* iw    = (const float*)d_in[1];
    const float* ib    = (const float*)d_in[2];
    const float* smu   = (const float*)d_in[3];
    const float* ssig  = (const float*)d_in[4];
    const float* sw    = (const float*)d_in[5];
    const float* serev = (const float*)d_in[6];
    const float* mu    = (const float*)d_in[7];
    const float* sigma = (const float*)d_in[8];
    const float* w     = (const float*)d_in[9];
    const float* erev  = (const float*)d_in[10];
    const float* gleak = (const float*)d_in[11];
    const float* vleak = (const float*)d_in[12];
    const float* cm    = (const float*)d_in[13];
    const float* ow    = (const float*)d_in[14];
    const float* ob    = (const float*)d_in[15];
    const float* fcw   = (const float*)d_in[16];
    const float* fcb   = (const float*)d_in[17];
    const int* smask   = (const int*)d_in[18];
    const int* mask    = (const int*)d_in[19];
    float* out = (float*)d_out;

    // ws layout: [outbuf: B*T f32][vstate: B*N f32][pqws: S*N float4][sens]
    float* outbuf = (float*)d_ws;
    float* vstate = outbuf + (long)BB * TT;
    float4* pqws  = (float4*)(vstate + (long)BB * NN);   // 16B-aligned (ck'd)
    float* sens   = (float*)(pqws + SS * NN);

    size_t fixed = ((size_t)BB * TT + (size_t)BB * NN) * sizeof(float)
                 + (size_t)SS * NN * sizeof(float4);
    long avail = (long)ws_size - (long)fixed;
    long per_step = (long)BB * 2 * NN * sizeof(float);
    int Tc = (int)(avail / per_step);
    if (Tc > TT) Tc = TT;
    if (Tc < 1)  Tc = 1;

    ltc_fold_kernel<<<3, 256, 0, stream>>>(iw, ib, smu, ssig, sw, serev,
                                           smask, pqws);

    for (int t0 = 0; t0 < TT; t0 += Tc) {
        int tc = (TT - t0 < Tc) ? (TT - t0) : Tc;
        long total_tb = (long)tc * BB;
        int ctb = (int)((total_tb + 255) / 256);
        ltc_sens_kernel<<<ctb * NN, 256, 0, stream>>>(x, pqws, sens, t0, tc);
        ltc_scan_kernel<<<BB, 64, 0, stream>>>(mu, sigma, w, erev, mask, gleak,
                                               vleak, cm, ow, ob, sens, outbuf,
                                               vstate, t0, tc, t0 == 0 ? 1 : 0);
    }
    ltc_fc_kernel<<<BB * NCLASS, 64, 0, stream>>>(outbuf, fcw, fcb, out);
}

// Round 10
// 2116.758 us; speedup vs baseline: 1.0840x; 1.0840x over previous
//
#include <hip/hip_runtime.h>

#define BB 256
#define TT 2048
#define SS 32
#define NN 19
#define NCLASS 10
#define NUNFOLD 6
#define EPSV 1e-8f
#define LOG2E 1.4426950408889634f
#define CH 128                 // timesteps per producer chunk
#define NCH (TT / CH)          // 16 chunks
#define SROW 38                // sens row: 19 num + 19 den

// ---------------------------------------------------------------------------
template <int CTRL>
__device__ __forceinline__ float dpp_shl(float x)
{
    return __int_as_float(__builtin_amdgcn_update_dpp(
        0, __float_as_int(x), CTRL, 0xf, 0xf, true));
}

__device__ __forceinline__ float bperm(int addr4, float v)
{
    return __int_as_float(__builtin_amdgcn_ds_bpermute(addr4, __float_as_int(v)));
}

// leader lane of pre-neuron i (rows 2,3 offset +1 => all 19 leaders in
// distinct LDS banks -> conflict-free bpermute broadcast)
__device__ __forceinline__ int lead_lane(int i)
{
    int rw = i / 5;
    return 16 * rw + 3 * (i % 5) + (rw >= 2 ? 1 : 0);
}

// ---------------------------------------------------------------------------
// Fused producer/consumer loop.  Wave 0 = R8 scan chain (measured 368
// cy/unfold).  Waves 1-3 = sensory producers filling a double-buffered LDS
// ring one chunk ahead.  One __syncthreads per chunk; producer chunk ~8us
// vs scan chunk ~118us, so sens is fully hidden behind the serial chain.
// ---------------------------------------------------------------------------
template <int KU>
__device__ __forceinline__ void fused_loop(
    int tid, int lane, int wid, int b, int jc,
    const float (&sg2)[8], const float (&sb2)[8],
    const float (&Aa)[8], const float (&Wm)[8], const int (&src4)[8],
    float cmt, float glvl, float cgl, float ow0, float ob0,
    const float* __restrict__ x,
    const float4* __restrict__ pq,   // LDS: folded sensory params [j*SS+s]
    float* __restrict__ sbuf,        // LDS: [2][CH][SROW]
    float* __restrict__ obuf)        // LDS: [TT] motor outputs
{
    float v = 0.f;
    for (int c = 0; c <= NCH; c++) {
        if (wid != 0) {
            if (c < NCH) {               // produce chunk c
                float* sb = sbuf + (c & 1) * (CH * SROW);
                const float* xb = x + ((long)b * TT + (long)c * CH) * SS;
                for (int o = tid - 64; o < CH * NN; o += 192) {
                    int tl = o / NN;
                    int j  = o - tl * NN;
                    const float4* xr4 = (const float4*)(xb + tl * SS);
                    const float4* pp  = pq + j * SS;
                    float num = 0.f, den = 0.f;
#pragma unroll
                    for (int q4 = 0; q4 < SS / 4; q4++) {
                        float4 xv = xr4[q4];
                        float4 c0 = pp[4 * q4 + 0];
                        float4 c1 = pp[4 * q4 + 1];
                        float4 c2 = pp[4 * q4 + 2];
                        float4 c3 = pp[4 * q4 + 3];
                        {
                            float e0 = __builtin_amdgcn_exp2f(fmaf(c0.y, xv.x, c0.x));
                            float e1 = __builtin_amdgcn_exp2f(fmaf(c1.y, xv.y, c1.x));
                            float t0v = 1.0f + e0, t1v = 1.0f + e1;
                            float rD = __builtin_amdgcn_rcpf(t0v * t1v);
                            num = fmaf(fmaf(c0.w, t1v, c1.w * t0v), rD, num);
                            den = fmaf(fmaf(c0.z, t1v, c1.z * t0v), rD, den);
                        }
                        {
                            float e0 = __builtin_amdgcn_exp2f(fmaf(c2.y, xv.z, c2.x));
                            float e1 = __builtin_amdgcn_exp2f(fmaf(c3.y, xv.w, c3.x));
                            float t0v = 1.0f + e0, t1v = 1.0f + e1;
                            float rD = __builtin_amdgcn_rcpf(t0v * t1v);
                            num = fmaf(fmaf(c2.w, t1v, c3.w * t0v), rD, num);
                            den = fmaf(fmaf(c2.z, t1v, c3.z * t0v), rD, den);
                        }
                    }
                    sb[tl * SROW + j]      = num;
                    sb[tl * SROW + NN + j] = den;
                }
            }
        } else if (c > 0) {              // scan chunk c-1
            const float* sb = sbuf + ((c - 1) & 1) * (CH * SROW);
            float sn = sb[jc], sd = sb[NN + jc];
            int tbase = (c - 1) * CH;
            for (int tl = 0; tl < CH; tl++) {
                float sn_nx = sn, sd_nx = sd;
                if (tl + 1 < CH) {       // prefetch (hidden by 6 unfolds)
                    sn_nx = sb[(tl + 1) * SROW + jc];
                    sd_nx = sb[(tl + 1) * SROW + NN + jc];
                }
                float nbase = glvl + sn, dbase = cgl + sd;
#pragma unroll
                for (int u = 0; u < NUNFOLD; u++) {
                    float vi[KU];
#pragma unroll
                    for (int k = 0; k < KU; k++) vi[k] = bperm(src4[k], v);
                    float n = fmaf(cmt, v, nbase);
                    float ev[KU];
#pragma unroll
                    for (int k = 0; k < KU; k++)
                        ev[k] = __builtin_amdgcn_exp2f(fmaf(sg2[k], vi[k], sb2[k]));
                    float pn = 0.f, pd = 0.f;
                    constexpr int NP = KU / 2;
#pragma unroll
                    for (int p = 0; p < NP; p++) {
                        float t0v = 1.0f + ev[2 * p];
                        float t1v = 1.0f + ev[2 * p + 1];
                        float rD  = __builtin_amdgcn_rcpf(t0v * t1v);
                        pn = fmaf(fmaf(Aa[2 * p], t1v, Aa[2 * p + 1] * t0v), rD, pn);
                        pd = fmaf(fmaf(Wm[2 * p], t1v, Wm[2 * p + 1] * t0v), rD, pd);
                    }
                    if (KU & 1) {
                        float s1 = __builtin_amdgcn_rcpf(1.0f + ev[KU - 1]);
                        pn = fmaf(Aa[KU - 1], s1, pn);
                        pd = fmaf(Wm[KU - 1], s1, pd);
                    }
                    // 3-lane DPP reduce: triple base lane gets the full sum
                    pn = pn + dpp_shl<0x101>(pn) + dpp_shl<0x102>(pn);
                    pd = pd + dpp_shl<0x101>(pd) + dpp_shl<0x102>(pd);
                    // all lanes update; only leader lanes are ever read
                    v = (n + pn) * __builtin_amdgcn_rcpf(dbase + pd);
                }
                if (lane == 0) obuf[tbase + tl] = fmaf(v, ow0, ob0);
                sn = sn_nx; sd = sd_nx;
            }
        }
        __syncthreads();
    }
}

// ---------------------------------------------------------------------------
// One block per batch element.  Wave 0 scans; waves 1-3 produce; all 4 waves
// run the FC epilogue from LDS.
// ---------------------------------------------------------------------------
__global__ void __launch_bounds__(256, 1)
ltc_fused_kernel(const float* __restrict__ x,
                 const float* __restrict__ iw,  const float* __restrict__ ib,
                 const float* __restrict__ smu, const float* __restrict__ ssig,
                 const float* __restrict__ sw,  const float* __restrict__ serev,
                 const int* __restrict__ smask,
                 const float* __restrict__ mu,  const float* __restrict__ sigma,
                 const float* __restrict__ w,   const float* __restrict__ erev,
                 const int* __restrict__ mask,
                 const float* __restrict__ gleak, const float* __restrict__ vleak,
                 const float* __restrict__ cm,
                 const float* __restrict__ ow,  const float* __restrict__ ob,
                 const float* __restrict__ fcw, const float* __restrict__ fcb,
                 float* __restrict__ out)
{
    __shared__ float4 pq[SS * NN];          // 9.7 KB folded sensory params
    __shared__ float  sbuf[2 * CH * SROW];  // 38.9 KB sens ring
    __shared__ float  obuf[TT];             // 8 KB motor outputs
    __shared__ float  red[4 * NCLASS];      // FC cross-wave reduce

    int tid  = threadIdx.x;
    int b    = blockIdx.x;
    int lane = tid & 63;
    int wid  = tid >> 6;

    // ---- fold sensory params into LDS: pq[j*SS+s] = {P, Qn, W, A} ----
    for (int idx = tid; idx < SS * NN; idx += 256) {
        int j = idx >> 5;
        int s = idx & 31;
        int src = s * NN + j;
        float sg = ssig[src] * LOG2E;
        float P  = sg * smu[src] - sg * ib[s];
        float Qn = -sg * iw[s];
        float wm = sw[src] * (float)smask[src];
        pq[idx] = make_float4(P, Qn, wm, wm * serev[src]);
    }

    // ---- scan-lane setup (replicated on all waves; depends only on lane,
    //      so every wave derives the identical km for uniform barriers) ----
    int row  = lane >> 4;
    int pos  = lane & 15;
    int off  = (row >= 2) ? 1 : 0;
    int posr = pos - off;
    int jq   = (posr < 0) ? 5 : posr / 3;
    int rr   = (posr < 0) ? 0 : posr - 3 * jq;
    int j    = row * 5 + jq;
    bool pad = (jq >= 5) || (j >= NN);
    int jc   = pad ? 0 : j;
    int r    = pad ? 0 : rr;

    float sg2[8], sb2[8], Aa[8], Wm[8];
    int src4[8];
    int used = 0;
#pragma unroll
    for (int s = 0; s < 8; s++) {
        int target = 3 * s + r;
        int ii = -1, a = 0;
        for (int i = 0; i < NN; i++) {
            if (mask[i * NN + jc] != 0) {
                if (a == target) ii = i;
                a++;
            }
        }
        bool ok = (ii >= 0) && !pad;
        int iu  = ok ? ii : 0;
        int idx = iu * NN + jc;
        float sgv = sigma[idx];
        float wmm = ok ? w[idx] : 0.f;
        sg2[s] = ok ? (-LOG2E * sgv) : 0.f;
        sb2[s] = ok ? (LOG2E * sgv * mu[idx]) : 0.f;
        Aa[s]  = wmm * erev[idx];
        Wm[s]  = wmm;
        src4[s] = lead_lane(iu) << 2;
        if (ok) used = s + 1;
    }
    int km = used;
#pragma unroll
    for (int o = 1; o < 64; o <<= 1) {
        int other = __shfl_xor(km, o, 64);
        km = km > other ? km : other;
    }

    float cmt   = cm[jc] * (float)NUNFOLD;
    float gl    = gleak[jc];
    float glvl  = gl * vleak[jc];
    float cgl   = cmt + gl + EPSV;
    float ow0 = ow[0], ob0 = ob[0];

    __syncthreads();   // pq ready before producers start chunk 0

    if (km <= 3)
        fused_loop<3>(tid, lane, wid, b, jc, sg2, sb2, Aa, Wm, src4,
                      cmt, glvl, cgl, ow0, ob0, x, pq, sbuf, obuf);
    else if (km == 4)
        fused_loop<4>(tid, lane, wid, b, jc, sg2, sb2, Aa, Wm, src4,
                      cmt, glvl, cgl, ow0, ob0, x, pq, sbuf, obuf);
    else if (km == 5)
        fused_loop<5>(tid, lane, wid, b, jc, sg2, sb2, Aa, Wm, src4,
                      cmt, glvl, cgl, ow0, ob0, x, pq, sbuf, obuf);
    else if (km == 6)
        fused_loop<6>(tid, lane, wid, b, jc, sg2, sb2, Aa, Wm, src4,
                      cmt, glvl, cgl, ow0, ob0, x, pq, sbuf, obuf);
    else
        fused_loop<7>(tid, lane, wid, b, jc, sg2, sb2, Aa, Wm, src4,
                      cmt, glvl, cgl, ow0, ob0, x, pq, sbuf, obuf);

    // ---- FC epilogue: out[b][c] = sum_t obuf[t]*fcw[c][t] + fcb[c] ----
    float acc[NCLASS];
#pragma unroll
    for (int c = 0; c < NCLASS; c++) acc[c] = 0.f;
    for (int t = tid; t < TT; t += 256) {
        float ov = obuf[t];
#pragma unroll
        for (int c = 0; c < NCLASS; c++)
            acc[c] = fmaf(ov, fcw[c * TT + t], acc[c]);
    }
#pragma unroll
    for (int c = 0; c < NCLASS; c++) {
#pragma unroll
        for (int o2 = 32; o2 > 0; o2 >>= 1)
            acc[c] += __shfl_down(acc[c], o2, 64);
    }
    if (lane == 0) {
#pragma unroll
        for (int c = 0; c < NCLASS; c++) red[wid * NCLASS + c] = acc[c];
    }
    __syncthreads();
    if (tid < NCLASS)
        out[b * NCLASS + tid] = red[tid] + red[NCLASS + tid]
                              + red[2 * NCLASS + tid] + red[3 * NCLASS + tid]
                              + fcb[tid];
}

// ---------------------------------------------------------------------------
extern "C" void kernel_launch(void* const* d_in, const int* in_sizes, int n_in,
                              void* d_out, int out_size, void* d_ws, size_t ws_size,
                              hipStream_t stream)
{
    const float* x     = (const float*)d_in[0];
    const float* iw    = (const float*)d_in[1];
    const float* ib    = (const float*)d_in[2];
    const float* smu   = (const float*)d_in[3];
    const float* ssig  = (const float*)d_in[4];
    const float* sw    = (const float*)d_in[5];
    const float* serev = (const float*)d_in[6];
    const float* mu    = (const float*)d_in[7];
    const float* sigma = (const float*)d_in[8];
    const float* w     = (const float*)d_in[9];
    const float* erev  = (const float*)d_in[10];
    const float* gleak = (const float*)d_in[11];
    const float* vleak = (const float*)d_in[12];
    const float* cm    = (const float*)d_in[13];
    const float* ow    = (const float*)d_in[14];
    const float* ob    = (const float*)d_in[15];
    const float* fcw   = (const float*)d_in[16];
    const float* fcb   = (const float*)d_in[17];
    const int* smask   = (const int*)d_in[18];
    const int* mask    = (const int*)d_in[19];
    float* out = (float*)d_out;

    ltc_fused_kernel<<<BB, 256, 0, stream>>>(x, iw, ib, smu, ssig, sw, serev,
                                             smask, mu, sigma, w, erev, mask,
                                             gleak, vleak, cm, ow, ob,
                                             fcw, fcb, out);
}

// Round 11
// 1786.226 us; speedup vs baseline: 1.2846x; 1.1850x over previous
//
#include <hip/hip_runtime.h>

#define BB 256
#define TT 2048
#define SS 32
#define NN 19
#define NCLASS 10
#define NUNFOLD 6
#define EPSV 1e-8f
#define LOG2E 1.4426950408889634f
#define CH 128                 // timesteps per producer chunk
#define NCH (TT / CH)          // 16 chunks
#define SROW 39                // sens row: 19 num + 19 den + 1 pad (bank-spread)

// ---------------------------------------------------------------------------
template <int CTRL>
__device__ __forceinline__ float dpp_shl(float x)
{
    return __int_as_float(__builtin_amdgcn_update_dpp(
        0, __float_as_int(x), CTRL, 0xf, 0xf, true));
}

__device__ __forceinline__ float bperm(int addr4, float v)
{
    return __int_as_float(__builtin_amdgcn_ds_bpermute(addr4, __float_as_int(v)));
}

// leader lane of pre-neuron i (rows 2,3 offset +1 => all 19 leaders in
// distinct LDS banks -> conflict-free bpermute broadcast)
__device__ __forceinline__ int lead_lane(int i)
{
    int rw = i / 5;
    return 16 * rw + 3 * (i % 5) + (rw >= 2 ? 1 : 0);
}

// ---------------------------------------------------------------------------
// Fused producer/consumer loop.  Wave 0 = R8 scan chain.  Waves 1-3 =
// sensory producers, THREAD = one tl, j/s as wave-uniform loops so every
// pq read is a same-address LDS broadcast (R10's lane-indexed (tl,j) made
// them 16-way bank conflicts -> 2.4e8 replays stalling the scan's bperms).
// ---------------------------------------------------------------------------
template <int KU>
__device__ __forceinline__ void fused_loop(
    int tid, int lane, int wid, int b, int jc,
    const float (&sg2)[8], const float (&sb2)[8],
    const float (&Aa)[8], const float (&Wm)[8], const int (&src4)[8],
    float cmt, float glvl, float cgl, float ow0, float ob0,
    const float* __restrict__ x,
    const float4* __restrict__ pq,   // LDS: folded sensory params [j*SS+s]
    float* __restrict__ sbuf,        // LDS: [2][CH][SROW]
    float* __restrict__ obuf)        // LDS: [TT] motor outputs
{
    float v = 0.f;
    for (int c = 0; c <= NCH; c++) {
        if (wid != 0) {
            if (c < NCH) {               // produce chunk c
                float* sb = sbuf + (c & 1) * (CH * SROW);
                const float* xb = x + ((long)b * TT + (long)c * CH) * SS;
                for (int tl = tid - 64; tl < CH; tl += 192) {
                    const float4* xr4 = (const float4*)(xb + tl * SS);
                    float xs[SS];
#pragma unroll
                    for (int q = 0; q < SS / 4; q++) {
                        float4 v4 = xr4[q];
                        xs[4 * q + 0] = v4.x; xs[4 * q + 1] = v4.y;
                        xs[4 * q + 2] = v4.z; xs[4 * q + 3] = v4.w;
                    }
                    float* srow = sb + tl * SROW;
                    for (int j = 0; j < NN; j++) {      // wave-uniform j
                        const float4* pp = pq + j * SS;
                        float num = 0.f, den = 0.f;
#pragma unroll 4
                        for (int s = 0; s < SS; s += 2) {
                            float4 c0 = pp[s];          // broadcast (uniform)
                            float4 c1 = pp[s + 1];
                            float e0 = __builtin_amdgcn_exp2f(fmaf(c0.y, xs[s], c0.x));
                            float e1 = __builtin_amdgcn_exp2f(fmaf(c1.y, xs[s + 1], c1.x));
                            float t0v = 1.0f + e0, t1v = 1.0f + e1;
                            float rD = __builtin_amdgcn_rcpf(t0v * t1v);
                            num = fmaf(fmaf(c0.w, t1v, c1.w * t0v), rD, num);
                            den = fmaf(fmaf(c0.z, t1v, c1.z * t0v), rD, den);
                        }
                        srow[j]      = num;             // stride-39 rows:
                        srow[NN + j] = den;             // 2-way banks = free
                    }
                }
            }
        } else if (c > 0) {              // scan chunk c-1
            const float* sb = sbuf + ((c - 1) & 1) * (CH * SROW);
            float sn = sb[jc], sd = sb[NN + jc];
            int tbase = (c - 1) * CH;
            for (int tl = 0; tl < CH; tl++) {
                float sn_nx = sn, sd_nx = sd;
                if (tl + 1 < CH) {       // prefetch (hidden by 6 unfolds)
                    sn_nx = sb[(tl + 1) * SROW + jc];
                    sd_nx = sb[(tl + 1) * SROW + NN + jc];
                }
                float nbase = glvl + sn, dbase = cgl + sd;
#pragma unroll
                for (int u = 0; u < NUNFOLD; u++) {
                    float vi[KU];
#pragma unroll
                    for (int k = 0; k < KU; k++) vi[k] = bperm(src4[k], v);
                    float n = fmaf(cmt, v, nbase);
                    float ev[KU];
#pragma unroll
                    for (int k = 0; k < KU; k++)
                        ev[k] = __builtin_amdgcn_exp2f(fmaf(sg2[k], vi[k], sb2[k]));
                    float pn = 0.f, pd = 0.f;
                    constexpr int NP = KU / 2;
#pragma unroll
                    for (int p = 0; p < NP; p++) {
                        float t0v = 1.0f + ev[2 * p];
                        float t1v = 1.0f + ev[2 * p + 1];
                        float rD  = __builtin_amdgcn_rcpf(t0v * t1v);
                        pn = fmaf(fmaf(Aa[2 * p], t1v, Aa[2 * p + 1] * t0v), rD, pn);
                        pd = fmaf(fmaf(Wm[2 * p], t1v, Wm[2 * p + 1] * t0v), rD, pd);
                    }
                    if (KU & 1) {
                        float s1 = __builtin_amdgcn_rcpf(1.0f + ev[KU - 1]);
                        pn = fmaf(Aa[KU - 1], s1, pn);
                        pd = fmaf(Wm[KU - 1], s1, pd);
                    }
                    // 3-lane DPP reduce: triple base lane gets the full sum
                    pn = pn + dpp_shl<0x101>(pn) + dpp_shl<0x102>(pn);
                    pd = pd + dpp_shl<0x101>(pd) + dpp_shl<0x102>(pd);
                    // all lanes update; only leader lanes are ever read
                    v = (n + pn) * __builtin_amdgcn_rcpf(dbase + pd);
                }
                if (lane == 0) obuf[tbase + tl] = fmaf(v, ow0, ob0);
                sn = sn_nx; sd = sd_nx;
            }
        }
        __syncthreads();
    }
}

// ---------------------------------------------------------------------------
// One block per batch element.  Wave 0 scans; waves 1-3 produce; all 4 waves
// run the FC epilogue from LDS.
// ---------------------------------------------------------------------------
__global__ void __launch_bounds__(256, 1)
ltc_fused_kernel(const float* __restrict__ x,
                 const float* __restrict__ iw,  const float* __restrict__ ib,
                 const float* __restrict__ smu, const float* __restrict__ ssig,
                 const float* __restrict__ sw,  const float* __restrict__ serev,
                 const int* __restrict__ smask,
                 const float* __restrict__ mu,  const float* __restrict__ sigma,
                 const float* __restrict__ w,   const float* __restrict__ erev,
                 const int* __restrict__ mask,
                 const float* __restrict__ gleak, const float* __restrict__ vleak,
                 const float* __restrict__ cm,
                 const float* __restrict__ ow,  const float* __restrict__ ob,
                 const float* __restrict__ fcw, const float* __restrict__ fcb,
                 float* __restrict__ out)
{
    __shared__ float4 pq[SS * NN];          // 9.7 KB folded sensory params
    __shared__ float  sbuf[2 * CH * SROW];  // 39.9 KB sens ring (stride 39)
    __shared__ float  obuf[TT];             // 8 KB motor outputs
    __shared__ float  red[4 * NCLASS];      // FC cross-wave reduce

    int tid  = threadIdx.x;
    int b    = blockIdx.x;
    int lane = tid & 63;
    int wid  = tid >> 6;

    // ---- fold sensory params into LDS: pq[j*SS+s] = {P, Qn, W, A} ----
    for (int idx = tid; idx < SS * NN; idx += 256) {
        int j = idx >> 5;
        int s = idx & 31;
        int src = s * NN + j;
        float sg = ssig[src] * LOG2E;
        float P  = sg * smu[src] - sg * ib[s];
        float Qn = -sg * iw[s];
        float wm = sw[src] * (float)smask[src];
        pq[idx] = make_float4(P, Qn, wm, wm * serev[src]);
    }

    // ---- scan-lane setup (replicated on all waves; depends only on lane,
    //      so every wave derives the identical km for uniform control) ----
    int row  = lane >> 4;
    int pos  = lane & 15;
    int off  = (row >= 2) ? 1 : 0;
    int posr = pos - off;
    int jq   = (posr < 0) ? 5 : posr / 3;
    int rr   = (posr < 0) ? 0 : posr - 3 * jq;
    int j    = row * 5 + jq;
    bool pad = (jq >= 5) || (j >= NN);
    int jc   = pad ? 0 : j;
    int r    = pad ? 0 : rr;

    float sg2[8], sb2[8], Aa[8], Wm[8];
    int src4[8];
    int used = 0;
#pragma unroll
    for (int s = 0; s < 8; s++) {
        int target = 3 * s + r;
        int ii = -1, a = 0;
        for (int i = 0; i < NN; i++) {
            if (mask[i * NN + jc] != 0) {
                if (a == target) ii = i;
                a++;
            }
        }
        bool ok = (ii >= 0) && !pad;
        int iu  = ok ? ii : 0;
        int idx = iu * NN + jc;
        float sgv = sigma[idx];
        float wmm = ok ? w[idx] : 0.f;
        sg2[s] = ok ? (-LOG2E * sgv) : 0.f;
        sb2[s] = ok ? (LOG2E * sgv * mu[idx]) : 0.f;
        Aa[s]  = wmm * erev[idx];
        Wm[s]  = wmm;
        src4[s] = lead_lane(iu) << 2;
        if (ok) used = s + 1;
    }
    int km = used;
#pragma unroll
    for (int o = 1; o < 64; o <<= 1) {
        int other = __shfl_xor(km, o, 64);
        km = km > other ? km : other;
    }

    float cmt   = cm[jc] * (float)NUNFOLD;
    float gl    = gleak[jc];
    float glvl  = gl * vleak[jc];
    float cgl   = cmt + gl + EPSV;
    float ow0 = ow[0], ob0 = ob[0];

    __syncthreads();   // pq ready before producers start chunk 0

    if (km <= 3)
        fused_loop<3>(tid, lane, wid, b, jc, sg2, sb2, Aa, Wm, src4,
                      cmt, glvl, cgl, ow0, ob0, x, pq, sbuf, obuf);
    else if (km == 4)
        fused_loop<4>(tid, lane, wid, b, jc, sg2, sb2, Aa, Wm, src4,
                      cmt, glvl, cgl, ow0, ob0, x, pq, sbuf, obuf);
    else if (km == 5)
        fused_loop<5>(tid, lane, wid, b, jc, sg2, sb2, Aa, Wm, src4,
                      cmt, glvl, cgl, ow0, ob0, x, pq, sbuf, obuf);
    else if (km == 6)
        fused_loop<6>(tid, lane, wid, b, jc, sg2, sb2, Aa, Wm, src4,
                      cmt, glvl, cgl, ow0, ob0, x, pq, sbuf, obuf);
    else
        fused_loop<7>(tid, lane, wid, b, jc, sg2, sb2, Aa, Wm, src4,
                      cmt, glvl, cgl, ow0, ob0, x, pq, sbuf, obuf);

    // ---- FC epilogue: out[b][c] = sum_t obuf[t]*fcw[c][t] + fcb[c] ----
    float acc[NCLASS];
#pragma unroll
    for (int c = 0; c < NCLASS; c++) acc[c] = 0.f;
    for (int t = tid; t < TT; t += 256) {
        float ov = obuf[t];
#pragma unroll
        for (int c = 0; c < NCLASS; c++)
            acc[c] = fmaf(ov, fcw[c * TT + t], acc[c]);
    }
#pragma unroll
    for (int c = 0; c < NCLASS; c++) {
#pragma unroll
        for (int o2 = 32; o2 > 0; o2 >>= 1)
            acc[c] += __shfl_down(acc[c], o2, 64);
    }
    if (lane == 0) {
#pragma unroll
        for (int c = 0; c < NCLASS; c++) red[wid * NCLASS + c] = acc[c];
    }
    __syncthreads();
    if (tid < NCLASS)
        out[b * NCLASS + tid] = red[tid] + red[NCLASS + tid]
                              + red[2 * NCLASS + tid] + red[3 * NCLASS + tid]
                              + fcb[tid];
}

// ---------------------------------------------------------------------------
extern "C" void kernel_launch(void* const* d_in, const int* in_sizes, int n_in,
                              void* d_out, int out_size, void* d_ws, size_t ws_size,
                              hipStream_t stream)
{
    const float* x     = (const float*)d_in[0];
    const float* iw    = (const float*)d_in[1];
    const float* ib    = (const float*)d_in[2];
    const float* smu   = (const float*)d_in[3];
    const float* ssig  = (const float*)d_in[4];
    const float* sw    = (const float*)d_in[5];
    const float* serev = (const float*)d_in[6];
    const float* mu    = (const float*)d_in[7];
    const float* sigma = (const float*)d_in[8];
    const float* w     = (const float*)d_in[9];
    const float* erev  = (const float*)d_in[10];
    const float* gleak = (const float*)d_in[11];
    const float* vleak = (const float*)d_in[12];
    const float* cm    = (const float*)d_in[13];
    const float* ow    = (const float*)d_in[14];
    const float* ob    = (const float*)d_in[15];
    const float* fcw   = (const float*)d_in[16];
    const float* fcb   = (const float*)d_in[17];
    const int* smask   = (const int*)d_in[18];
    const int* mask    = (const int*)d_in[19];
    float* out = (float*)d_out;

    ltc_fused_kernel<<<BB, 256, 0, stream>>>(x, iw, ib, smu, ssig, sw, serev,
                                             smask, mu, sigma, w, erev, mask,
                                             gleak, vleak, cm, ow, ob,
                                             fcw, fcb, out);
}